// Round 19
// baseline (42.506 us; speedup 1.0000x reference)
//
#include <hip/hip_runtime.h>
#include <hip/hip_bf16.h>

// Problem constants (fixed by setup_inputs)
#define BB   4
#define CF   256
#define CC   64
#define CP   80
#define HH   128   // hi-res
#define WW   128
#define KK   25
#define NPIX 16384 // 128*128

typedef __attribute__((ext_vector_type(8))) short short8v;
typedef __attribute__((ext_vector_type(4))) short short4v;
typedef __attribute__((ext_vector_type(4))) float f32x4;
typedef __attribute__((ext_vector_type(2))) float f32x2;

static __device__ __forceinline__ short f2bf(float f) {
  __hip_bfloat16 h = __float2bfloat16(f);
  return *reinterpret_cast<short*>(&h);
}

// =================== K1: compress (1x1 conv) via bf16 MFMA ==============
// (byte-identical to round 17/18 — HBM-bound at ~82% of achievable BW)
__global__ __launch_bounds__(256) void k_compress(
    const float* __restrict__ feat, const float* __restrict__ wc,
    const float* __restrict__ bc, const float* __restrict__ we,
    short* __restrict__ guide, short* __restrict__ webF) {
  __shared__ short Al[32 * 520];  // [(cblk*4+lh)][o(64)*8], pad 512->520
  __shared__ short Bl[64 * 72];   // [px][c 0..63], stride 72
  const int tid = threadIdx.x;
  const int bx = blockIdx.x;
  const int b = bx >> 8;
  const int y = (bx >> 1) & 127;
  const int x0 = (bx & 1) << 6;

  // distributed webF prestage in fragment order (mapping HW-verified r15)
  {
    int j = bx * 256 + tid;
    if (j < 9 * 32 * 64) {
      int tap = j >> 11, kk = (j >> 6) & 31, c = j & 63;
      float v = (kk < KK) ? we[(kk * 64 + c) * 9 + tap] : 0.f;
      int c8 = c >> 3, e = c & 7;
      int frag = tap * 4 + ((kk >> 4) << 1) + (c8 >> 2);
      int lane = (kk & 15) | ((c8 & 3) << 4);
      webF[frag * 512 + lane * 8 + e] = f2bf(v);
    }
  }

  // convert wc (64x256 f32) -> Al in fragment order
#pragma unroll
  for (int t = 0; t < 8; ++t) {
    int idx = tid + t * 256;  // 0..2047
    int o = idx >> 5, c8 = idx & 31;
    const f32x4* src = (const f32x4*)(wc + o * CF + c8 * 8);
    f32x4 v0 = src[0], v1 = src[1];
    short8v h;
    h[0] = f2bf(v0.x); h[1] = f2bf(v0.y); h[2] = f2bf(v0.z); h[3] = f2bf(v0.w);
    h[4] = f2bf(v1.x); h[5] = f2bf(v1.y); h[6] = f2bf(v1.z); h[7] = f2bf(v1.w);
    int cblk = c8 >> 2, lh4 = c8 & 3;
    *(short8v*)(Al + (cblk * 4 + lh4) * 520 + o * 8) = h;
  }

  const int wave = tid >> 6, l = tid & 63;
  const int l15 = l & 15, lh = l >> 4;
  const int px_s = tid & 63;          // staging pixel
  const int c_s = (tid >> 6) << 4;    // staging channel offset (16/wave)
  const float* fb = feat + (size_t)b * CF * NPIX + y * WW + x0;

  f32x4 acc[4];
#pragma unroll
  for (int m = 0; m < 4; ++m) acc[m] = (f32x4){0.f, 0.f, 0.f, 0.f};

  for (int c0 = 0; c0 < CF; c0 += 64) {
    if (c0) __syncthreads();
    float v[16];
#pragma unroll
    for (int i = 0; i < 16; ++i)
      v[i] = fb[(size_t)(c0 + c_s + i) * NPIX + px_s];
    short8v h0, h1;
#pragma unroll
    for (int e = 0; e < 8; ++e) { h0[e] = f2bf(v[e]); h1[e] = f2bf(v[8 + e]); }
    *(short8v*)(Bl + px_s * 72 + c_s) = h0;
    *(short8v*)(Bl + px_s * 72 + c_s + 8) = h1;
    __syncthreads();  // Bl (and, first pass, Al) visible
#pragma unroll
    for (int ks = 0; ks < 64; ks += 32) {
      const int cblk = (c0 + ks) >> 5;
      short8v bfr = *(const short8v*)(Bl + (wave * 16 + l15) * 72 + ks + lh * 8);
#pragma unroll
      for (int m = 0; m < 4; ++m) {
        short8v a = *(const short8v*)(Al + (cblk * 4 + lh) * 520 +
                                      (m * 16 + l15) * 8);
        acc[m] = __builtin_amdgcn_mfma_f32_16x16x32_bf16(a, bfr, acc[m], 0, 0, 0);
      }
    }
  }

  // epilogue: +bias, cvt bf16, store [b][y][x][c]
  const int px = wave * 16 + l15;
  short* gb = guide + ((size_t)((b * HH + y) * WW + x0 + px)) * CC;
#pragma unroll
  for (int m = 0; m < 4; ++m) {
    short4v o;
#pragma unroll
    for (int r = 0; r < 4; ++r) {
      int c = m * 16 + lh * 4 + r;
      o[r] = f2bf(acc[m][r] + bc[c]);
    }
    *(short4v*)(gb + m * 16 + lh * 4) = o;
  }
}

// ====== K2: fused conv+softmax+carafe — SINGLE-PASS 80-ch carafe ========
// r18 body with the two sequential carafe halves merged: Pl widened to
// [cell64][102] (all 80 ch, slot == channel), all 20 pred loads T14-issued
// before conv, written back once post-conv. One fewer barrier pair, 125 vs
// 150 LDS reads/thread. LDS 33.8 KB -> 4 blocks/CU.
__global__ __launch_bounds__(256, 4) void k_fused(
    const short* __restrict__ guide, const short* __restrict__ webF,
    const float* __restrict__ be, const float* __restrict__ pred,
    float* __restrict__ out) {
  __shared__ char smem[7680 + 26112];
  short* Gl = (short*)smem;               // [y'10][x'10][c72] = 14400 B
  float* Ml = (float*)smem;               // [px64][30] = 7680 B (post-conv)
  float* Pl = (float*)(smem + 7680);      // [cell64][102] = 26112 B (post-conv)
  const int tid = threadIdx.x;
  const int bx = blockIdx.x;
  const int b = bx >> 8;
  const int t = bx & 255;
  const int y0 = (t >> 4) << 3, x0 = (t & 15) << 3;
  const int wave = tid >> 6, l = tid & 63;
  const int l15 = l & 15, lh = l >> 4;

  // ---- stage guide halo tile (zero-pad) ----
  for (int idx = tid; idx < 10 * 10 * 8; idx += 256) {
    int yp = idx / 80;
    int rem = idx - yp * 80;
    int xp = rem >> 3, cq = (rem & 7) << 3;
    int gy = y0 - 1 + yp, gx = x0 - 1 + xp;
    short8v v = {0, 0, 0, 0, 0, 0, 0, 0};
    if (gy >= 0 && gy < HH && gx >= 0 && gx < WW)
      v = *(const short8v*)(guide + ((size_t)((b * HH + gy) * WW + gx)) * CC + cq);
    *(short8v*)(Gl + (yp * 10 + xp) * 72 + cq) = v;
  }

  // ---- T14 issue: ALL 80-ch pred loads -> registers (hide under conv) --
  const int ylo = (y0 >> 1) - 2, xlo = (x0 >> 1) - 2;
  float pv[20];
#pragma unroll
  for (int it = 0; it < 20; ++it) {
    int idx = it * 256 + tid;          // 0..5119
    int c = idx >> 6;                  // 0..79
    int cell = idx & 63;
    int r = cell >> 3, cl = cell & 7;
    int ry = ylo + r;
    ry = ry < 0 ? -ry : (ry > 63 ? 126 - ry : ry);
    int rx = xlo + cl;
    rx = rx < 0 ? -rx : (rx > 63 ? 126 - rx : rx);
    pv[it] = pred[(((size_t)(b * CP + c)) << 12) + (ry << 6) + rx];
  }
  __syncthreads();  // Gl ready

  // ---- conv MFMA (pv loads in flight underneath) ----
  const int r_ = wave * 2 + (l15 >> 3);  // tile row 0..7
  const int cx = l15 & 7;                // tile col 0..7
  f32x4 acc0 = {0.f, 0.f, 0.f, 0.f}, acc1 = {0.f, 0.f, 0.f, 0.f};
#pragma unroll
  for (int tap = 0; tap < 9; ++tap) {
    const int dy = tap / 3, dx = tap - dy * 3;
#pragma unroll
    for (int ks32 = 0; ks32 < 2; ++ks32) {
      short8v a0 = *(const short8v*)(webF + (tap * 4 + ks32) * 512 + l * 8);
      short8v a1 = *(const short8v*)(webF + (tap * 4 + 2 + ks32) * 512 + l * 8);
      short8v bf = *(const short8v*)(Gl + ((r_ + dy) * 10 + cx + dx) * 72 +
                                     ks32 * 32 + lh * 8);
      acc0 = __builtin_amdgcn_mfma_f32_16x16x32_bf16(a0, bf, acc0, 0, 0, 0);
      acc1 = __builtin_amdgcn_mfma_f32_16x16x32_bf16(a1, bf, acc1, 0, 0, 0);
    }
  }

  // ---- bias + softmax over kk (25 vals in 4 lanes: xor 16,32) ----
  float sv[8];
#pragma unroll
  for (int r = 0; r < 4; ++r) {
    int kk0 = lh * 4 + r;            // 0..15, always < 25
    sv[r] = acc0[r] + be[kk0];
    int kk1 = 16 + lh * 4 + r;       // 16..31
    sv[4 + r] = (kk1 < KK) ? (acc1[r] + be[kk1]) : -1e30f;
  }
  float mx = sv[0];
#pragma unroll
  for (int i = 1; i < 8; ++i) mx = fmaxf(mx, sv[i]);
  mx = fmaxf(mx, __shfl_xor(mx, 16));
  mx = fmaxf(mx, __shfl_xor(mx, 32));
  float s = 0.f;
#pragma unroll
  for (int i = 0; i < 8; ++i) {
    sv[i] = __expf(sv[i] - mx);
    s += sv[i];
  }
  s += __shfl_xor(s, 16);
  s += __shfl_xor(s, 32);
  float inv = 1.f / s;

  __syncthreads();  // ALL waves done reading Gl; region becomes Ml/Pl

  // ---- write Ml[px][30] + write-back pv -> Pl[cell][102] ----
  {
    int pxm = wave * 16 + l15;  // == r_*8 + cx
#pragma unroll
    for (int r = 0; r < 4; ++r) {
      Ml[pxm * 30 + lh * 4 + r] = sv[r] * inv;
      if (lh < 3) Ml[pxm * 30 + 16 + lh * 4 + r] = sv[4 + r] * inv;
    }
  }
#pragma unroll
  for (int it = 0; it < 20; ++it) {
    int idx = it * 256 + tid;
    int c = idx >> 6;
    int cell = idx & 63;
    Pl[cell * 102 + c] = pv[it];
  }
  __syncthreads();  // Ml + Pl ready

  // ---- carafe: thread = px-pair x 10-ch group, single pass ----
  const int g = tid >> 5;              // 0..7 -> 10-ch group
  const int pr = tid & 31;             // pry(0..7) x prx(0..3)
  const int pry = pr >> 2, prx = pr & 3;
  const int Y = y0 + pry, X = x0 + prx * 2;

  // hoist pair masks
  float m[2][KK];
#pragma unroll
  for (int dxp = 0; dxp < 2; ++dxp) {
    const float* mb = Ml + (pry * 8 + prx * 2 + dxp) * 30;
#pragma unroll
    for (int q = 0; q < 7; ++q) {
      f32x2 lo = *(const f32x2*)(mb + q * 4);
      f32x2 hi = *(const f32x2*)(mb + q * 4 + 2);
      int kk = q * 4;
      m[dxp][kk] = lo.x;
      if (kk + 1 < KK) m[dxp][kk + 1] = lo.y;
      if (kk + 2 < KK) m[dxp][kk + 2] = hi.x;
      if (kk + 3 < KK) m[dxp][kk + 3] = hi.y;
    }
  }

  float acc[10][2];
#pragma unroll
  for (int cc = 0; cc < 10; ++cc) { acc[cc][0] = 0.f; acc[cc][1] = 0.f; }

  const float* Pbase = Pl + ((pry >> 1) * 8 + prx) * 102 + g * 10;
#pragma unroll
  for (int i = 0; i < 5; ++i)
#pragma unroll
    for (int j = 0; j < 5; ++j) {
      const float* P = Pbase + (i * 8 + j) * 102;
      f32x2 p01 = *(const f32x2*)(P);
      f32x2 p23 = *(const f32x2*)(P + 2);
      f32x2 p45 = *(const f32x2*)(P + 4);
      f32x2 p67 = *(const f32x2*)(P + 6);
      f32x2 p89 = *(const f32x2*)(P + 8);
      float m0 = m[0][i * 5 + j], m1 = m[1][i * 5 + j];
      acc[0][0] += p01.x * m0; acc[0][1] += p01.x * m1;
      acc[1][0] += p01.y * m0; acc[1][1] += p01.y * m1;
      acc[2][0] += p23.x * m0; acc[2][1] += p23.x * m1;
      acc[3][0] += p23.y * m0; acc[3][1] += p23.y * m1;
      acc[4][0] += p45.x * m0; acc[4][1] += p45.x * m1;
      acc[5][0] += p45.y * m0; acc[5][1] += p45.y * m1;
      acc[6][0] += p67.x * m0; acc[6][1] += p67.x * m1;
      acc[7][0] += p67.y * m0; acc[7][1] += p67.y * m1;
      acc[8][0] += p89.x * m0; acc[8][1] += p89.x * m1;
      acc[9][0] += p89.y * m0; acc[9][1] += p89.y * m1;
    }

#pragma unroll
  for (int cc = 0; cc < 10; ++cc) {
    float* ob = out + (((size_t)(b * CP + g * 10 + cc)) << 14) + Y * WW + X;
    f32x2 v2 = {acc[cc][0], acc[cc][1]};
    *(f32x2*)ob = v2;
  }
}

extern "C" void kernel_launch(void* const* d_in, const int* in_sizes, int n_in,
                              void* d_out, int out_size, void* d_ws,
                              size_t ws_size, hipStream_t stream) {
  (void)in_sizes; (void)n_in; (void)out_size; (void)ws_size;
  const float* pred = (const float*)d_in[0];  // (4,80,64,64)
  const float* feat = (const float*)d_in[1];  // (4,256,128,128)
  const float* wc   = (const float*)d_in[2];  // (64,256)
  const float* bc   = (const float*)d_in[3];  // (64)
  const float* we   = (const float*)d_in[4];  // (25,64,3,3)
  const float* be   = (const float*)d_in[5];  // (25)
  float* out = (float*)d_out;                 // (4,80,128,128)

  char* ws = (char*)d_ws;
  short* guide = (short*)ws;             // 8,388,608 B bf16 [b][y][x][c]
  short* webF  = (short*)(ws + 8388608); // 36,864 B bf16 fragment-order

  hipLaunchKernelGGL(k_compress, dim3(1024), dim3(256), 0, stream,
                     feat, wc, bc, we, guide, webF);
  hipLaunchKernelGGL(k_fused, dim3(1024), dim3(256), 0, stream,
                     guide, webF, be, pred, out);
}

// Round 20
// 42.296 us; speedup vs baseline: 1.0050x; 1.0050x over previous
//
#include <hip/hip_runtime.h>
#include <hip/hip_bf16.h>

// Problem constants (fixed by setup_inputs)
#define BB   4
#define CF   256
#define CC   64
#define CP   80
#define HH   128   // hi-res
#define WW   128
#define KK   25
#define NPIX 16384 // 128*128

typedef __attribute__((ext_vector_type(8))) short short8v;
typedef __attribute__((ext_vector_type(4))) short short4v;
typedef __attribute__((ext_vector_type(4))) float f32x4;
typedef __attribute__((ext_vector_type(2))) float f32x2;

static __device__ __forceinline__ short f2bf(float f) {
  __hip_bfloat16 h = __float2bfloat16(f);
  return *reinterpret_cast<short*>(&h);
}

// =================== K1: compress (1x1 conv) via bf16 MFMA ==============
// HBM-bound at ~92% of effective achievable BW (75 MB in ~13 us).
__global__ __launch_bounds__(256) void k_compress(
    const float* __restrict__ feat, const float* __restrict__ wc,
    const float* __restrict__ bc, const float* __restrict__ we,
    short* __restrict__ guide, short* __restrict__ webF) {
  __shared__ short Al[32 * 520];  // [(cblk*4+lh)][o(64)*8], pad 512->520
  __shared__ short Bl[64 * 72];   // [px][c 0..63], stride 72
  const int tid = threadIdx.x;
  const int bx = blockIdx.x;
  const int b = bx >> 8;
  const int y = (bx >> 1) & 127;
  const int x0 = (bx & 1) << 6;

  // distributed webF prestage in fragment order (mapping HW-verified r15)
  {
    int j = bx * 256 + tid;
    if (j < 9 * 32 * 64) {
      int tap = j >> 11, kk = (j >> 6) & 31, c = j & 63;
      float v = (kk < KK) ? we[(kk * 64 + c) * 9 + tap] : 0.f;
      int c8 = c >> 3, e = c & 7;
      int frag = tap * 4 + ((kk >> 4) << 1) + (c8 >> 2);
      int lane = (kk & 15) | ((c8 & 3) << 4);
      webF[frag * 512 + lane * 8 + e] = f2bf(v);
    }
  }

  // convert wc (64x256 f32) -> Al in fragment order
#pragma unroll
  for (int t = 0; t < 8; ++t) {
    int idx = tid + t * 256;  // 0..2047
    int o = idx >> 5, c8 = idx & 31;
    const f32x4* src = (const f32x4*)(wc + o * CF + c8 * 8);
    f32x4 v0 = src[0], v1 = src[1];
    short8v h;
    h[0] = f2bf(v0.x); h[1] = f2bf(v0.y); h[2] = f2bf(v0.z); h[3] = f2bf(v0.w);
    h[4] = f2bf(v1.x); h[5] = f2bf(v1.y); h[6] = f2bf(v1.z); h[7] = f2bf(v1.w);
    int cblk = c8 >> 2, lh4 = c8 & 3;
    *(short8v*)(Al + (cblk * 4 + lh4) * 520 + o * 8) = h;
  }

  const int wave = tid >> 6, l = tid & 63;
  const int l15 = l & 15, lh = l >> 4;
  const int px_s = tid & 63;          // staging pixel
  const int c_s = (tid >> 6) << 4;    // staging channel offset (16/wave)
  const float* fb = feat + (size_t)b * CF * NPIX + y * WW + x0;

  f32x4 acc[4];
#pragma unroll
  for (int m = 0; m < 4; ++m) acc[m] = (f32x4){0.f, 0.f, 0.f, 0.f};

  for (int c0 = 0; c0 < CF; c0 += 64) {
    if (c0) __syncthreads();
    float v[16];
#pragma unroll
    for (int i = 0; i < 16; ++i)
      v[i] = fb[(size_t)(c0 + c_s + i) * NPIX + px_s];
    short8v h0, h1;
#pragma unroll
    for (int e = 0; e < 8; ++e) { h0[e] = f2bf(v[e]); h1[e] = f2bf(v[8 + e]); }
    *(short8v*)(Bl + px_s * 72 + c_s) = h0;
    *(short8v*)(Bl + px_s * 72 + c_s + 8) = h1;
    __syncthreads();  // Bl (and, first pass, Al) visible
#pragma unroll
    for (int ks = 0; ks < 64; ks += 32) {
      const int cblk = (c0 + ks) >> 5;
      short8v bfr = *(const short8v*)(Bl + (wave * 16 + l15) * 72 + ks + lh * 8);
#pragma unroll
      for (int m = 0; m < 4; ++m) {
        short8v a = *(const short8v*)(Al + (cblk * 4 + lh) * 520 +
                                      (m * 16 + l15) * 8);
        acc[m] = __builtin_amdgcn_mfma_f32_16x16x32_bf16(a, bfr, acc[m], 0, 0, 0);
      }
    }
  }

  // epilogue: +bias, cvt bf16, store [b][y][x][c]
  const int px = wave * 16 + l15;
  short* gb = guide + ((size_t)((b * HH + y) * WW + x0 + px)) * CC;
#pragma unroll
  for (int m = 0; m < 4; ++m) {
    short4v o;
#pragma unroll
    for (int r = 0; r < 4; ++r) {
      int c = m * 16 + lh * 4 + r;
      o[r] = f2bf(acc[m][r] + bc[c]);
    }
    *(short4v*)(gb + m * 16 + lh * 4) = o;
  }
}

// ====== K2: fused conv+softmax+carafe — T14 async-STAGE pred loads ======
// Round-18 champion: fragment-order webF read straight from global
// (lane-linear 1KB segments, L1-hot), lean 20.5 KB LDS, pred loads
// issued early (pv0 under conv MFMA, pv1 under carafe half-0) and
// written to LDS late — HBM/L2 latency hidden under compute.
__global__ __launch_bounds__(256, 4) void k_fused(
    const short* __restrict__ guide, const short* __restrict__ webF,
    const float* __restrict__ be, const float* __restrict__ pred,
    float* __restrict__ out) {
  __shared__ char smem[20480];
  short* Gl = (short*)smem;               // [y'10][x'10][c72] = 14400 B
  float* Ml = (float*)smem;               // [px64][30] = 7680 B (post-conv)
  float* Pl = (float*)(smem + 7680);      // [cell64][50] = 12800 B (post-conv)
  const int tid = threadIdx.x;
  const int bx = blockIdx.x;
  const int b = bx >> 8;
  const int t = bx & 255;
  const int y0 = (t >> 4) << 3, x0 = (t & 15) << 3;
  const int wave = tid >> 6, l = tid & 63;
  const int l15 = l & 15, lh = l >> 4;

  // ---- stage guide halo tile (zero-pad) ----
  for (int idx = tid; idx < 10 * 10 * 8; idx += 256) {
    int yp = idx / 80;
    int rem = idx - yp * 80;
    int xp = rem >> 3, cq = (rem & 7) << 3;
    int gy = y0 - 1 + yp, gx = x0 - 1 + xp;
    short8v v = {0, 0, 0, 0, 0, 0, 0, 0};
    if (gy >= 0 && gy < HH && gx >= 0 && gx < WW)
      v = *(const short8v*)(guide + ((size_t)((b * HH + gy) * WW + gx)) * CC + cq);
    *(short8v*)(Gl + (yp * 10 + xp) * 72 + cq) = v;
  }

  // ---- T14 issue: half-0 pred loads -> registers (hide under conv) ----
  const int ylo = (y0 >> 1) - 2, xlo = (x0 >> 1) - 2;
  int pcell[10], pslot[10];  // cached addressing for the write-back
#pragma unroll
  for (int it = 0; it < 10; ++it) {
    int idx = it * 256 + tid;
    int c = idx >> 6;
    int cell = idx & 63;
    int gg = c / 5, cc = c - gg * 5;
    pcell[it] = cell;
    pslot[it] = gg * 6 + cc;
  }
  float pv0[10];
#pragma unroll
  for (int it = 0; it < 10; ++it) {
    int idx = it * 256 + tid;
    int c = idx >> 6;
    int cell = idx & 63;
    int r = cell >> 3, cl = cell & 7;
    int ry = ylo + r;
    ry = ry < 0 ? -ry : (ry > 63 ? 126 - ry : ry);
    int rx = xlo + cl;
    rx = rx < 0 ? -rx : (rx > 63 ? 126 - rx : rx);
    pv0[it] = pred[(((size_t)(b * CP + c)) << 12) + (ry << 6) + rx];
  }
  __syncthreads();  // Gl ready

  // ---- conv MFMA (pv0 loads in flight underneath) ----
  const int r_ = wave * 2 + (l15 >> 3);  // tile row 0..7
  const int cx = l15 & 7;                // tile col 0..7
  f32x4 acc0 = {0.f, 0.f, 0.f, 0.f}, acc1 = {0.f, 0.f, 0.f, 0.f};
#pragma unroll
  for (int tap = 0; tap < 9; ++tap) {
    const int dy = tap / 3, dx = tap - dy * 3;
#pragma unroll
    for (int ks32 = 0; ks32 < 2; ++ks32) {
      short8v a0 = *(const short8v*)(webF + (tap * 4 + ks32) * 512 + l * 8);
      short8v a1 = *(const short8v*)(webF + (tap * 4 + 2 + ks32) * 512 + l * 8);
      short8v bf = *(const short8v*)(Gl + ((r_ + dy) * 10 + cx + dx) * 72 +
                                     ks32 * 32 + lh * 8);
      acc0 = __builtin_amdgcn_mfma_f32_16x16x32_bf16(a0, bf, acc0, 0, 0, 0);
      acc1 = __builtin_amdgcn_mfma_f32_16x16x32_bf16(a1, bf, acc1, 0, 0, 0);
    }
  }

  // ---- bias + softmax over kk (25 vals in 4 lanes: xor 16,32) ----
  float sv[8];
#pragma unroll
  for (int r = 0; r < 4; ++r) {
    int kk0 = lh * 4 + r;            // 0..15, always < 25
    sv[r] = acc0[r] + be[kk0];
    int kk1 = 16 + lh * 4 + r;       // 16..31
    sv[4 + r] = (kk1 < KK) ? (acc1[r] + be[kk1]) : -1e30f;
  }
  float mx = sv[0];
#pragma unroll
  for (int i = 1; i < 8; ++i) mx = fmaxf(mx, sv[i]);
  mx = fmaxf(mx, __shfl_xor(mx, 16));
  mx = fmaxf(mx, __shfl_xor(mx, 32));
  float s = 0.f;
#pragma unroll
  for (int i = 0; i < 8; ++i) {
    sv[i] = __expf(sv[i] - mx);
    s += sv[i];
  }
  s += __shfl_xor(s, 16);
  s += __shfl_xor(s, 32);
  float inv = 1.f / s;

  __syncthreads();  // ALL waves done reading Gl; region becomes Ml/Pl

  // ---- write Ml[px][30] + write-back pv0 -> Pl ----
  {
    int pxm = wave * 16 + l15;  // == r_*8 + cx
#pragma unroll
    for (int r = 0; r < 4; ++r) {
      Ml[pxm * 30 + lh * 4 + r] = sv[r] * inv;
      if (lh < 3) Ml[pxm * 30 + 16 + lh * 4 + r] = sv[4 + r] * inv;
    }
  }
#pragma unroll
  for (int it = 0; it < 10; ++it)
    Pl[pcell[it] * 50 + pslot[it]] = pv0[it];

  // ---- T14 issue: half-1 pred loads (hide under carafe half-0) ----
  float pv1[10];
#pragma unroll
  for (int it = 0; it < 10; ++it) {
    int idx = it * 256 + tid;
    int c = idx >> 6;
    int cell = idx & 63;
    int r = cell >> 3, cl = cell & 7;
    int ry = ylo + r;
    ry = ry < 0 ? -ry : (ry > 63 ? 126 - ry : ry);
    int rx = xlo + cl;
    rx = rx < 0 ? -rx : (rx > 63 ? 126 - rx : rx);
    pv1[it] = pred[(((size_t)(b * CP + 40 + c)) << 12) + (ry << 6) + rx];
  }
  __syncthreads();  // Ml + Pl(half0) ready

  // ---- carafe thread roles (r15) ----
  const int g = tid >> 5;              // 0..7 -> 5-ch group
  const int pr = tid & 31;             // pry(0..7) x prx(0..3)
  const int pry = pr >> 2, prx = pr & 3;
  const int Y = y0 + pry, X = x0 + prx * 2;
  const float* Pbase = Pl + ((pry >> 1) * 8 + prx) * 50 + g * 6;

  // hoist pair masks once — same for both halves
  float m[2][KK];
#pragma unroll
  for (int dxp = 0; dxp < 2; ++dxp) {
    const float* mb = Ml + (pry * 8 + prx * 2 + dxp) * 30;
#pragma unroll
    for (int q = 0; q < 7; ++q) {
      f32x2 lo = *(const f32x2*)(mb + q * 4);
      f32x2 hi = *(const f32x2*)(mb + q * 4 + 2);
      int kk = q * 4;
      m[dxp][kk] = lo.x;
      if (kk + 1 < KK) m[dxp][kk + 1] = lo.y;
      if (kk + 2 < KK) m[dxp][kk + 2] = hi.x;
      if (kk + 3 < KK) m[dxp][kk + 3] = hi.y;
    }
  }

  for (int half = 0; half < 2; ++half) {
    if (half == 1) {
      __syncthreads();  // Pl(half0) dead
#pragma unroll
      for (int it = 0; it < 10; ++it)
        Pl[pcell[it] * 50 + pslot[it]] = pv1[it];
      __syncthreads();  // Pl(half1) ready
    }

    float acc[5][2];
#pragma unroll
    for (int cc = 0; cc < 5; ++cc) { acc[cc][0] = 0.f; acc[cc][1] = 0.f; }

#pragma unroll
    for (int i = 0; i < 5; ++i)
#pragma unroll
      for (int j = 0; j < 5; ++j) {
        const float* P = Pbase + (i * 8 + j) * 50;
        f32x2 p01 = *(const f32x2*)(P);
        f32x2 p23 = *(const f32x2*)(P + 2);
        float p4 = P[4];
        float m0 = m[0][i * 5 + j], m1 = m[1][i * 5 + j];
        acc[0][0] += p01.x * m0; acc[0][1] += p01.x * m1;
        acc[1][0] += p01.y * m0; acc[1][1] += p01.y * m1;
        acc[2][0] += p23.x * m0; acc[2][1] += p23.x * m1;
        acc[3][0] += p23.y * m0; acc[3][1] += p23.y * m1;
        acc[4][0] += p4    * m0; acc[4][1] += p4    * m1;
      }

#pragma unroll
    for (int cc = 0; cc < 5; ++cc) {
      float* ob = out + (((size_t)(b * CP + half * 40 + g * 5 + cc)) << 14) +
                  Y * WW + X;
      f32x2 v2 = {acc[cc][0], acc[cc][1]};
      *(f32x2*)ob = v2;
    }
  }
}

extern "C" void kernel_launch(void* const* d_in, const int* in_sizes, int n_in,
                              void* d_out, int out_size, void* d_ws,
                              size_t ws_size, hipStream_t stream) {
  (void)in_sizes; (void)n_in; (void)out_size; (void)ws_size;
  const float* pred = (const float*)d_in[0];  // (4,80,64,64)
  const float* feat = (const float*)d_in[1];  // (4,256,128,128)
  const float* wc   = (const float*)d_in[2];  // (64,256)
  const float* bc   = (const float*)d_in[3];  // (64)
  const float* we   = (const float*)d_in[4];  // (25,64,3,3)
  const float* be   = (const float*)d_in[5];  // (25)
  float* out = (float*)d_out;                 // (4,80,128,128)

  char* ws = (char*)d_ws;
  short* guide = (short*)ws;             // 8,388,608 B bf16 [b][y][x][c]
  short* webF  = (short*)(ws + 8388608); // 36,864 B bf16 fragment-order

  hipLaunchKernelGGL(k_compress, dim3(1024), dim3(256), 0, stream,
                     feat, wc, bc, we, guide, webF);
  hipLaunchKernelGGL(k_fused, dim3(1024), dim3(256), 0, stream,
                     guide, webF, be, pred, out);
}